// Round 1
// baseline (127.643 us; speedup 1.0000x reference)
//
#include <hip/hip_runtime.h>

// Fused 2-level inverse Haar DWT (UnPatcher, PATCH_SIZE=4).
// Input  x:   [8, 256, 96, 96]  fp32
// Output out: [8, 16, 384, 384] fp32
//
// Each thread: one (b, g, p, q). Reads 16 channel values at (p,q), applies the
// 2-level +/-1 butterfly (per-level scale 2*S*S == 1), writes one 4x4 output
// tile as 4 contiguous float4 stores.

#define B_  8
#define CIN 256
#define G_  16
#define H_  96
#define W_  96
#define OW  384

__global__ __launch_bounds__(256) void idwt2_fused(const float* __restrict__ x,
                                                   float* __restrict__ out) {
    const int N = B_ * G_ * H_ * W_;
    int idx = blockIdx.x * blockDim.x + threadIdx.x;
    if (idx >= N) return;

    int q  = idx % W_;
    int t1 = idx / W_;
    int p  = t1 % H_;
    int t2 = t1 / H_;
    int g  = t2 % G_;
    int b  = t2 / G_;

    const size_t plane = (size_t)H_ * W_;  // 9216
    const float* xin = x + (size_t)b * CIN * plane + (size_t)p * W_ + q;

    // v[k][m] = x[b, g + 16k + 64m, p, q]
    float v[4][4];
#pragma unroll
    for (int k = 0; k < 4; ++k) {
#pragma unroll
        for (int m = 0; m < 4; ++m) {
            v[k][m] = xin[(size_t)(g + 16 * k + 64 * m) * plane];
        }
    }

    // Level 1 (inner): t[k][dh][dw] = v0 + (-1)^dh v1 + (-1)^dw v2 + (-1)^(dh+dw) v3
    float t[4][2][2];
#pragma unroll
    for (int k = 0; k < 4; ++k) {
        float u0 = v[k][0] + v[k][1];
        float u1 = v[k][0] - v[k][1];
        float u2 = v[k][2] + v[k][3];
        float u3 = v[k][2] - v[k][3];
        t[k][0][0] = u0 + u2;
        t[k][0][1] = u0 - u2;
        t[k][1][0] = u1 + u3;
        t[k][1][1] = u1 - u3;
    }

    // Level 2 (outer): out[4p + 2dh + eh, 4q + 2dw + ew]
    float rowv[4][4];
#pragma unroll
    for (int dh = 0; dh < 2; ++dh) {
#pragma unroll
        for (int dw = 0; dw < 2; ++dw) {
            float a0 = t[0][dh][dw] + t[1][dh][dw];
            float a1 = t[0][dh][dw] - t[1][dh][dw];
            float a2 = t[2][dh][dw] + t[3][dh][dw];
            float a3 = t[2][dh][dw] - t[3][dh][dw];
            rowv[2 * dh + 0][2 * dw + 0] = a0 + a2;
            rowv[2 * dh + 0][2 * dw + 1] = a0 - a2;
            rowv[2 * dh + 1][2 * dw + 0] = a1 + a3;
            rowv[2 * dh + 1][2 * dw + 1] = a1 - a3;
        }
    }

    float* obase = out + ((size_t)(b * G_ + g) * OW + 4 * (size_t)p) * OW + 4 * (size_t)q;
#pragma unroll
    for (int r = 0; r < 4; ++r) {
        float4 f4 = make_float4(rowv[r][0], rowv[r][1], rowv[r][2], rowv[r][3]);
        *reinterpret_cast<float4*>(obase + (size_t)r * OW) = f4;
    }
}

extern "C" void kernel_launch(void* const* d_in, const int* in_sizes, int n_in,
                              void* d_out, int out_size, void* d_ws, size_t ws_size,
                              hipStream_t stream) {
    const float* x = (const float*)d_in[0];
    float* out = (float*)d_out;
    const int N = B_ * G_ * H_ * W_;          // 1,179,648
    const int block = 256;
    const int grid = (N + block - 1) / block; // 4608
    idwt2_fused<<<grid, block, 0, stream>>>(x, out);
}